// Round 4
// baseline (246645.801 us; speedup 1.0000x reference)
//
#include <hip/hip_runtime.h>
#include <hip/hip_bf16.h>

// B=32, T_ENC=512, steps=501, N_MEL=160, H=1024, 4H=4096
// aLSTM K=1792 (pre256|ctx512|ah1024), dLSTM K=2560 (ctx512|ah1024|dh1024)
// fp32 I/O; bf16 staged weights; persistent kernel w/ hand-rolled grid barrier.

typedef __hip_bfloat16 bf16;

__device__ __forceinline__ bf16 f2b(float x){ return __float2bfloat16(x); }
__device__ __forceinline__ float bfu(unsigned short u){
  union{unsigned int i; float f;} v; v.i = ((unsigned int)u)<<16; return v.f; }
__device__ __forceinline__ float sig_s(float x){
  if (x > 30.f) return 1.f; if (x < -30.f) return 0.f;
  return 1.f/(1.f+__expf(-x)); }
__device__ __forceinline__ float tanh_s(float x){
  if (x > 15.f) return 1.f; if (x < -15.f) return -1.f;
  float e=__expf(2.f*x); return 1.f-2.f/(e+1.f); }

constexpr int NB = 256;

// ---- workspace (fp32 element offsets) ----
constexpr size_t S_MK2  = 32ull*512*128;
constexpr size_t OFF_MK2  = 0;
constexpr size_t OFF_CTX2 = OFF_MK2 + S_MK2;          // 2*32*512
constexpr size_t OFF_AH2  = OFF_CTX2 + 2ull*32*512;   // 2*32*1024
constexpr size_t OFF_DH2  = OFF_AH2 + 2ull*32*1024;   // 2*32*1024
constexpr size_t OFF_AC   = OFF_DH2 + 2ull*32*1024;
constexpr size_t OFF_DC   = OFF_AC + 32ull*1024;
constexpr size_t OFF_AW   = OFF_DC + 32ull*1024;
constexpr size_t OFF_AWT  = OFF_AW + 32ull*512;
constexpr size_t OFF_BAR  = OFF_AWT + 32ull*512;      // 16 ints
constexpr size_t ZERO_LEN = (OFF_BAR + 16) - OFF_CTX2;  // 262,160
constexpr size_t OFF_PBUF = OFF_BAR + 16;             // 32*512
constexpr size_t OFF_PSUM = OFF_PBUF + 32ull*512;     // 256
constexpr size_t OFF_CTXP = OFF_PSUM + 256;           // 32*8*512
constexpr size_t OFF_BIASA= OFF_CTXP + 32ull*8*512;
constexpr size_t OFF_BIASD= OFF_BIASA + 4096;
constexpr size_t OFF_F32_END = OFF_BIASD + 4096;

constexpr size_t OFF_PRE2B = ((OFF_F32_END*4 + 255)/256)*256;   // bytes
constexpr size_t S_PRE2B = 501ull*32*256;                       // bf16
constexpr size_t OFF_WAC = ((OFF_PRE2B + S_PRE2B*2 + 255)/256)*256;
constexpr size_t S_WAC = 4096ull*1792;                          // bf16
constexpr size_t OFF_WDC = OFF_WAC + S_WAC*2;
constexpr size_t S_WDC = 4096ull*2560;                          // bf16
constexpr size_t WS_NEEDED = OFF_WDC + S_WDC*2;                 // ~53.9 MB

// output offsets (fp32 elements)
constexpr size_t OUT_MEL  = 0;
constexpr size_t OUT_GATE = 501ull*32*160;
constexpr size_t OUT_ATTN = OUT_GATE + 501ull*32;

// ---------------- prep kernels ----------------
__global__ void k_zero(float* __restrict__ p, int n){
  int i = blockIdx.x*256 + threadIdx.x;
  if (i < n) p[i] = 0.f;
}
__global__ void k_bias(const float* __restrict__ b1, const float* __restrict__ b2,
                       float* __restrict__ out){
  int i = blockIdx.x*256 + threadIdx.x;
  if (i < 4096) out[i] = b1[i] + b2[i];
}
// concat wih|whh rows -> bf16 [4096][K]
__global__ void k_wcat(const float* __restrict__ wih, int kih,
                       const float* __restrict__ whh, bf16* __restrict__ dst, int K){
  size_t i = (size_t)blockIdx.x*256 + threadIdx.x;
  size_t total = 4096ull*(size_t)K;
  if (i >= total) return;
  int j = (int)(i / K); int k = (int)(i - (size_t)j*K);
  float v = (k < kih) ? wih[(size_t)j*kih + k] : whh[(size_t)j*1024 + (k - kih)];
  dst[i] = f2b(v);
}
// prenet -> pre2b[tt][b][256] bf16
__global__ __launch_bounds__(256) void k_prenet(const float* __restrict__ mels,
    const float* __restrict__ w1, const float* __restrict__ b1,
    const float* __restrict__ w2, const float* __restrict__ b2,
    bf16* __restrict__ pre2){
  __shared__ float mel[160];
  __shared__ float x1[256];
  int b = blockIdx.x, tid = threadIdx.x;
  for (int ti = 0; ti < 8; ++ti){
    int tt = blockIdx.y*8 + ti;
    if (tt >= 501) break;
    if (tid < 160) mel[tid] = (tt == 0) ? 0.f : mels[((size_t)b*500 + (tt-1))*160 + tid];
    __syncthreads();
    float a = b1[tid];
    for (int k = 0; k < 160; ++k) a += mel[k]*w1[tid*160 + k];
    x1[tid] = fmaxf(a, 0.f);
    __syncthreads();
    float a2 = b2[tid];
    for (int k = 0; k < 256; ++k) a2 += x1[k]*w2[tid*256 + k];
    pre2[((size_t)tt*32 + b)*256 + tid] = f2b(fmaxf(a2, 0.f));
    __syncthreads();
  }
}
// mk2[b][t][c] = enc[b][t]·wk[c] + bk[c]
__global__ __launch_bounds__(128) void k_memkeys(const float* __restrict__ enc,
    const float* __restrict__ wk, const float* __restrict__ bk, float* __restrict__ mk2){
  __shared__ float er[512];
  int b = blockIdx.x, tid = threadIdx.x;
  for (int i = 0; i < 8; ++i){
    int t = blockIdx.y*8 + i;
    const float* e = enc + ((size_t)b*512 + t)*512;
    for (int k = tid; k < 512; k += 128) er[k] = e[k];
    __syncthreads();
    float a = bk[tid];
    for (int k = 0; k < 512; ++k) a += er[k]*wk[tid*512 + k];
    mk2[((size_t)b*512 + t)*128 + tid] = a;
    __syncthreads();
  }
}

// ---------------- persistent decoder kernel ----------------
__device__ __forceinline__ float dot_f32(const float* __restrict__ x,
    const unsigned short* __restrict__ wu, int n, float acc){
  for (int k = 0; k < n; k += 8){
    float4 x0 = *(const float4*)(x+k);
    float4 x1 = *(const float4*)(x+k+4);
    ushort4 w0 = *(const ushort4*)(wu+k);
    ushort4 w1 = *(const ushort4*)(wu+k+4);
    acc = fmaf(x0.x, bfu(w0.x), acc); acc = fmaf(x0.y, bfu(w0.y), acc);
    acc = fmaf(x0.z, bfu(w0.z), acc); acc = fmaf(x0.w, bfu(w0.w), acc);
    acc = fmaf(x1.x, bfu(w1.x), acc); acc = fmaf(x1.y, bfu(w1.y), acc);
    acc = fmaf(x1.z, bfu(w1.z), acc); acc = fmaf(x1.w, bfu(w1.w), acc);
  }
  return acc;
}
__device__ __forceinline__ float dot_bf(const unsigned short* __restrict__ x,
    const unsigned short* __restrict__ wu, int n, float acc){
  for (int k = 0; k < n; k += 8){
    ushort4 x0 = *(const ushort4*)(x+k);
    ushort4 x1 = *(const ushort4*)(x+k+4);
    ushort4 w0 = *(const ushort4*)(wu+k);
    ushort4 w1 = *(const ushort4*)(wu+k+4);
    acc = fmaf(bfu(x0.x), bfu(w0.x), acc); acc = fmaf(bfu(x0.y), bfu(w0.y), acc);
    acc = fmaf(bfu(x0.z), bfu(w0.z), acc); acc = fmaf(bfu(x0.w), bfu(w0.w), acc);
    acc = fmaf(bfu(x1.x), bfu(w1.x), acc); acc = fmaf(bfu(x1.y), bfu(w1.y), acc);
    acc = fmaf(bfu(x1.z), bfu(w1.z), acc); acc = fmaf(bfu(x1.w), bfu(w1.w), acc);
  }
  return acc;
}

__device__ __forceinline__ void gridbar(int* __restrict__ bar){
  __syncthreads();
  if (threadIdx.x == 0){
    __threadfence();
    int* cnt = bar; int* gen = bar + 1;
    int g = __hip_atomic_load(gen, __ATOMIC_RELAXED, __HIP_MEMORY_SCOPE_AGENT);
    int v = __hip_atomic_fetch_add(cnt, 1, __ATOMIC_ACQ_REL, __HIP_MEMORY_SCOPE_AGENT);
    if (v == NB-1){
      __hip_atomic_store(cnt, 0, __ATOMIC_RELAXED, __HIP_MEMORY_SCOPE_AGENT);
      __hip_atomic_store(gen, g+1, __ATOMIC_RELEASE, __HIP_MEMORY_SCOPE_AGENT);
    } else {
      while (__hip_atomic_load(gen, __ATOMIC_RELAXED, __HIP_MEMORY_SCOPE_AGENT) == g)
        __builtin_amdgcn_s_sleep(4);
    }
    __threadfence();
  }
  __syncthreads();
}

__global__ __launch_bounds__(512, 4) void k_dec(
    const float* __restrict__ mk2, const unsigned short* __restrict__ pre2b,
    const unsigned short* __restrict__ WaC, const unsigned short* __restrict__ WdC,
    const float* __restrict__ biasA, const float* __restrict__ biasD,
    float* __restrict__ ctx2, float* __restrict__ ah2, float* __restrict__ dh2,
    float* __restrict__ ac, float* __restrict__ dc,
    float* __restrict__ aw, float* __restrict__ awt,
    float* __restrict__ pbuf, float* __restrict__ psum, float* __restrict__ ctxp,
    int* __restrict__ bar,
    const float* __restrict__ enc, const unsigned char* __restrict__ mask,
    const float* __restrict__ wq, const float* __restrict__ bq,
    const float* __restrict__ wl, const float* __restrict__ bl,
    const float* __restrict__ wa, const float* __restrict__ ba,
    const float* __restrict__ conv_w, const float* __restrict__ conv_b,
    const float* __restrict__ wm, const float* __restrict__ bm,
    const float* __restrict__ wg, const float* __restrict__ bg,
    float* __restrict__ melOut, float* __restrict__ gateOut, float* __restrict__ attnOut){

  __shared__ union {
    float sg[512];
    struct {
      float sq[128];
      float qp[4][128];
      float aw_s[96], awt_s[96];
      float rv[64][36];
      float ps[64];
    } a;
  } sm;

  const int blk = blockIdx.x, tid = threadIdx.x;
  // P1 mapping: 512 thr = 16 (gate-rows) x 32 (batch)
  const int b1 = tid & 31, jj = tid >> 5;
  const int g = jj >> 2, uu = jj & 3;
  const int u0 = blk*4;
  const int jA = (g<<10) + u0 + uu;

  for (int tau = 0; tau <= 501; ++tau){
    const int cur = tau & 1, prev = cur ^ 1;

    // ======== P1: gates_d+cell_d(tau-1), gates_a+cell_a(tau) ========
    if (tau >= 1){
      const unsigned short* w = WdC + (size_t)jA*2560;
      const float* cx  = ctx2 + prev*16384 + b1*512;
      const float* ahp = ah2 + (size_t)prev*32768 + b1*1024;
      const float* dhp = dh2 + (size_t)cur*32768 + b1*1024;   // dh(tau-2)
      float acc = dot_f32(cx, w, 512, 0.f);
      acc = dot_f32(ahp, w+512, 1024, acc);
      acc = dot_f32(dhp, w+1536, 1024, acc);
      sm.sg[jj*32 + b1] = acc;
      __syncthreads();
      if (tid < 128){
        int bb = tid & 31, ul = tid >> 5;
        int u = u0 + ul;
        float gi = sm.sg[(0+ul)*32+bb]  + biasD[u];
        float gf = sm.sg[(4+ul)*32+bb]  + biasD[1024+u];
        float gg = sm.sg[(8+ul)*32+bb]  + biasD[2048+u];
        float go = sm.sg[(12+ul)*32+bb] + biasD[3072+u];
        float cp = dc[bb*1024+u];
        float cn = sig_s(gf)*cp + sig_s(gi)*tanh_s(gg);
        dh2[(size_t)prev*32768 + bb*1024 + u] = sig_s(go)*tanh_s(cn);
        dc[bb*1024+u] = cn;
      }
      __syncthreads();
    }
    if (tau <= 500){
      const unsigned short* w = WaC + (size_t)jA*1792;
      const unsigned short* pr = pre2b + ((size_t)tau*32 + b1)*256;
      const float* cx  = ctx2 + prev*16384 + b1*512;
      const float* ahp = ah2 + (size_t)prev*32768 + b1*1024;
      float acc = dot_bf(pr, w, 256, 0.f);
      acc = dot_f32(cx, w+256, 512, acc);
      acc = dot_f32(ahp, w+768, 1024, acc);
      sm.sg[jj*32 + b1] = acc;
      __syncthreads();
      if (tid < 128){
        int bb = tid & 31, ul = tid >> 5;
        int u = u0 + ul;
        float gi = sm.sg[(0+ul)*32+bb]  + biasA[u];
        float gf = sm.sg[(4+ul)*32+bb]  + biasA[1024+u];
        float gg = sm.sg[(8+ul)*32+bb]  + biasA[2048+u];
        float go = sm.sg[(12+ul)*32+bb] + biasA[3072+u];
        float cp = ac[bb*1024+u];
        float cn = sig_s(gf)*cp + sig_s(gi)*tanh_s(gg);
        ah2[(size_t)cur*32768 + bb*1024 + u] = sig_s(go)*tanh_s(cn);
        ac[bb*1024+u] = cn;
      }
    }
    gridbar(bar);

    // ======== P2: attention energies (32b x 8 t-ranges) + out(tau-1) ========
    if (tau <= 500){
      const int b = blk >> 3, tr = blk & 7, tbase = tr*64;
      { // query partials
        int c = tid & 127, kp = tid >> 7;
        const float* ahq = ah2 + (size_t)cur*32768 + b*1024 + kp*256;
        const float* wqr = wq + (size_t)c*1024 + kp*256;
        float p = 0.f;
        for (int k = 0; k < 256; k += 4){
          float4 xv = *(const float4*)(ahq+k);
          float4 wv = *(const float4*)(wqr+k);
          p += xv.x*wv.x + xv.y*wv.y + xv.z*wv.z + xv.w*wv.w;
        }
        sm.a.qp[kp][c] = p;
      }
      if (tid < 94){
        int pos = tbase - 15 + tid;
        sm.a.aw_s[tid] = (pos >= 0 && pos < 512) ? aw[b*512+pos] : 0.f;
      } else if (tid < 188){
        int i = tid - 94; int pos = tbase - 15 + i;
        sm.a.awt_s[i] = (pos >= 0 && pos < 512) ? awt[b*512+pos] : 0.f;
      }
      __syncthreads();
      if (tid < 128){ // finalize sq[c] = q + bq + bl + wl·conv_b
        int c = tid;
        float q = sm.a.qp[0][c]+sm.a.qp[1][c]+sm.a.qp[2][c]+sm.a.qp[3][c] + bq[c] + bl[c];
        const float* wlr = wl + c*32;
        float ex = 0.f;
        for (int o = 0; o < 32; ++o) ex += wlr[o]*conv_b[o];
        sm.a.sq[c] = q + ex;
      }
      // conv: thread (tl, cp) does 4 output channels
      {
        int tl = tid >> 3, cp = tid & 7;
        float a0=0.f, a1=0.f, a2=0.f, a3=0.f;
        const float* c0 = conv_w + (cp*4+0)*62;
        const float* c1 = conv_w + (cp*4+1)*62;
        const float* c2 = conv_w + (cp*4+2)*62;
        const float* c3 = conv_w + (cp*4+3)*62;
        for (int k = 0; k < 31; ++k){
          float v0 = sm.a.aw_s[tl+k], v1 = sm.a.awt_s[tl+k];
          a0 += c0[k]*v0 + c0[31+k]*v1;
          a1 += c1[k]*v0 + c1[31+k]*v1;
          a2 += c2[k]*v0 + c2[31+k]*v1;
          a3 += c3[k]*v0 + c3[31+k]*v1;
        }
        sm.a.rv[tl][cp*4+0] = a0; sm.a.rv[tl][cp*4+1] = a1;
        sm.a.rv[tl][cp*4+2] = a2; sm.a.rv[tl][cp*4+3] = a3;
      }
      __syncthreads();
      // energy
      {
        int tl = tid >> 3, cp = tid & 7;
        int t = tbase + tl;
        float rvr[32];
        #pragma unroll
        for (int o = 0; o < 32; ++o) rvr[o] = sm.a.rv[tl][o];
        const float* mkrow = mk2 + ((size_t)(b*512 + t))*128 + cp*16;
        const float* sqp = sm.a.sq + cp*16;
        float eacc = 0.f;
        #pragma unroll
        for (int ci = 0; ci < 16; ++ci){
          int c = cp*16 + ci;
          const float* wlr = wl + c*32;
          float lc = 0.f;
          #pragma unroll
          for (int o = 0; o < 32; o += 4){
            float4 wv = *(const float4*)(wlr+o);
            lc += wv.x*rvr[o] + wv.y*rvr[o+1] + wv.z*rvr[o+2] + wv.w*rvr[o+3];
          }
          eacc += wa[c]*tanh_s(sqp[ci] + mkrow[ci] + lc);
        }
        eacc += __shfl_down(eacc, 4, 8);
        eacc += __shfl_down(eacc, 2, 8);
        eacc += __shfl_down(eacc, 1, 8);
        if (cp == 0){
          float e = eacc + ba[0];
          float p = mask[b*512 + t] ? 0.f : __expf(e);
          sm.a.ps[tl] = p;
          pbuf[b*512 + t] = p;
        }
      }
      __syncthreads();
      if (tid < 64){ // partial sum
        float v = sm.a.ps[tid];
        #pragma unroll
        for (int off = 32; off > 0; off >>= 1) v += __shfl_down(v, off, 64);
        if (tid == 0) psum[b*8 + tr] = v;
      }
      { // partial ctx
        float acc = 0.f;
        const float* ebase = enc + ((size_t)(b*512 + tbase))*512 + tid;
        for (int tl = 0; tl < 64; ++tl)
          acc = fmaf(sm.a.ps[tl], ebase[(size_t)tl*512], acc);
        ctxp[((b*8 + tr)<<9) + tid] = acc;
      }
    }
    if (tau >= 1){ // out projection for step tau-1
      int wv = blk*8 + (tid>>6), lane = tid & 63;
      for (int idx = wv; idx < 5152; idx += 2048){
        int b2 = idx/161, j = idx - b2*161;
        const float* row = (j < 160) ? (wm + (size_t)j*1536) : wg;
        const float* dhb = dh2 + (size_t)prev*32768 + b2*1024;
        const float* cxb = ctx2 + prev*16384 + b2*512;
        float acc = 0.f;
        for (int k = lane; k < 1536; k += 64){
          float x = (k < 1024) ? dhb[k] : cxb[k-1024];
          acc = fmaf(x, row[k], acc);
        }
        #pragma unroll
        for (int off = 32; off > 0; off >>= 1) acc += __shfl_down(acc, off, 64);
        if (lane == 0){
          if (j < 160) melOut[(size_t)(tau-1)*5120 + b2*160 + j] = acc + bm[j];
          else gateOut[(size_t)(tau-1)*32 + b2] = acc + bg[0];
        }
      }
    }
    gridbar(bar);

    // ======== P3: softmax finalize + ctx ========
    if (tau <= 500 && blk < 32){
      int b = blk;
      float S = 0.f;
      #pragma unroll
      for (int i = 0; i < 8; ++i)
        S += __hip_atomic_load(&psum[b*8+i], __ATOMIC_RELAXED, __HIP_MEMORY_SCOPE_AGENT);
      float inv = 1.f/S;
      int t = tid;
      float p = pbuf[b*512+t]*inv;
      aw[b*512+t] = p;
      awt[b*512+t] += p;
      attnOut[(size_t)tau*16384 + b*512 + t] = p;
      float cacc = 0.f;
      #pragma unroll
      for (int r = 0; r < 8; ++r) cacc += ctxp[((b*8+r)<<9) + t];
      ctx2[cur*16384 + b*512 + t] = cacc*inv;
    }
    gridbar(bar);
  }
}

// ---------------- launch ----------------
extern "C" void kernel_launch(void* const* d_in, const int* in_sizes, int n_in,
                              void* d_out, int out_size, void* d_ws, size_t ws_size,
                              hipStream_t stream){
  if (ws_size < WS_NEEDED) return;

  const float* enc    = (const float*)d_in[0];
  const float* mels   = (const float*)d_in[1];
  const unsigned char* mask = (const unsigned char*)d_in[2];
  const float* w_pre1 = (const float*)d_in[3];
  const float* b_pre1 = (const float*)d_in[4];
  const float* w_pre2 = (const float*)d_in[5];
  const float* b_pre2 = (const float*)d_in[6];
  const float* wih_a  = (const float*)d_in[7];
  const float* whh_a  = (const float*)d_in[8];
  const float* bih_a  = (const float*)d_in[9];
  const float* bhh_a  = (const float*)d_in[10];
  const float* wq     = (const float*)d_in[11];
  const float* bq     = (const float*)d_in[12];
  const float* wk     = (const float*)d_in[13];
  const float* bk     = (const float*)d_in[14];
  const float* conv_w = (const float*)d_in[15];
  const float* conv_b = (const float*)d_in[16];
  const float* wl     = (const float*)d_in[17];
  const float* bl     = (const float*)d_in[18];
  const float* wa     = (const float*)d_in[19];
  const float* ba     = (const float*)d_in[20];
  const float* wih_d  = (const float*)d_in[21];
  const float* whh_d  = (const float*)d_in[22];
  const float* bih_d  = (const float*)d_in[23];
  const float* bhh_d  = (const float*)d_in[24];
  const float* wm     = (const float*)d_in[25];
  const float* bm     = (const float*)d_in[26];
  const float* wg     = (const float*)d_in[27];
  const float* bg     = (const float*)d_in[28];

  float* W = (float*)d_ws;
  float* mk2  = W + OFF_MK2;
  float* ctx2 = W + OFF_CTX2;
  float* ah2  = W + OFF_AH2;
  float* dh2  = W + OFF_DH2;
  float* ac   = W + OFF_AC;
  float* dc   = W + OFF_DC;
  float* aw   = W + OFF_AW;
  float* awt  = W + OFF_AWT;
  int*   bar  = (int*)(W + OFF_BAR);
  float* pbuf = W + OFF_PBUF;
  float* psum = W + OFF_PSUM;
  float* ctxp = W + OFF_CTXP;
  float* biasA= W + OFF_BIASA;
  float* biasD= W + OFF_BIASD;
  unsigned short* pre2b = (unsigned short*)((char*)d_ws + OFF_PRE2B);
  bf16* WaC = (bf16*)((char*)d_ws + OFF_WAC);
  bf16* WdC = (bf16*)((char*)d_ws + OFF_WDC);

  float* out    = (float*)d_out;
  float* melOut = out + OUT_MEL;
  float* gateOut= out + OUT_GATE;
  float* attnOut= out + OUT_ATTN;

  // prep
  k_zero<<<(int)((ZERO_LEN + 255)/256), 256, 0, stream>>>(ctx2, (int)ZERO_LEN);
  k_bias<<<16, 256, 0, stream>>>(bih_a, bhh_a, biasA);
  k_bias<<<16, 256, 0, stream>>>(bih_d, bhh_d, biasD);
  k_wcat<<<(int)((S_WAC + 255)/256), 256, 0, stream>>>(wih_a, 768, whh_a, WaC, 1792);
  k_wcat<<<(int)((S_WDC + 255)/256), 256, 0, stream>>>(wih_d, 1536, whh_d, WdC, 2560);
  k_prenet<<<dim3(32, 63), 256, 0, stream>>>(mels, w_pre1, b_pre1, w_pre2, b_pre2, (bf16*)pre2b);
  k_memkeys<<<dim3(32, 64), 128, 0, stream>>>(enc, wk, bk, mk2);

  // persistent decoder
  k_dec<<<NB, 512, 0, stream>>>(mk2, pre2b,
      (const unsigned short*)WaC, (const unsigned short*)WdC, biasA, biasD,
      ctx2, ah2, dh2, ac, dc, aw, awt, pbuf, psum, ctxp, bar,
      enc, mask, wq, bq, wl, bl, wa, ba, conv_w, conv_b, wm, bm, wg, bg,
      melOut, gateOut, attnOut);
}